// Round 1
// baseline (250.966 us; speedup 1.0000x reference)
//
#include <hip/hip_runtime.h>
#include <math.h>

#define DEV static __device__ __forceinline__

constexpr int Bn = 32, Tn = 1024, Vn = 1024, Ln = 100, Sn = 2 * Ln + 1; // S=201
constexpr int   RW   = 208;          // compact lp_ext row: 201 states + pad = 52*float4 = 832 B
constexpr float LN2F = 0.6931471805599453f;
constexpr int   TILE = 32;           // timesteps per register tile (32 x float4 = 128 VGPR)

// DPP wavefront shift-right by 1 (lane i <- lane i-1), VALU pipe — no LDS latency.
// dpp_ctrl 0x138 = WAVE_SHR1 (gfx9/CDNA). bound_ctrl=false -> lane 0 keeps `old`.
DEV float dpp_up1_f(float v) {                     // lane0 -> 0.0f
    return __builtin_bit_cast(float,
        __builtin_amdgcn_update_dpp(0, __builtin_bit_cast(int, v), 0x138, 0xf, 0xf, false));
}
DEV int dpp_up1_i(int v) {                         // lane0 -> own value (old = v)
    return __builtin_amdgcn_update_dpp(v, v, 0x138, 0xf, 0xf, false);
}

DEV float wave_max(float m) {
    #pragma unroll
    for (int off = 32; off; off >>= 1) m = fmaxf(m, __shfl_xor(m, off));
    return m;
}
DEV float wave_sum(float s) {
    #pragma unroll
    for (int off = 32; off; off >>= 1) s += __shfl_xor(s, off);
    return s;
}

// Kernel 1: two (b,t) rows per 256-thread block (2 independent loads -> MLP=2).
// Emits PROBABILITIES, compact rows: lp_ext[row*RW + s] = exp(logits[row, ext[s]] - lse(row)).
__global__ __launch_bounds__(256) void pre_kernel(const int* __restrict__ targets,
                                                  const float* __restrict__ logits,
                                                  float* __restrict__ lp_ext) {
    __shared__ float rows[2][Vn];     // 8 KB
    __shared__ float red[2][8];
    const int t    = threadIdx.x;
    const int lane = t & 63;
    const int wid  = t >> 6;
    const int r0   = blockIdx.x * 2;      // rows r0, r0+1 share the same b (Tn even)
    const int b    = r0 >> 10;

    float4 v0 = ((const float4*)(logits + (size_t)r0 * Vn))[t];
    float4 v1 = ((const float4*)(logits + (size_t)(r0 + 1) * Vn))[t];
    ((float4*)rows[0])[t] = v0;
    ((float4*)rows[1])[t] = v1;

    float m0 = fmaxf(fmaxf(v0.x, v0.y), fmaxf(v0.z, v0.w));
    float m1 = fmaxf(fmaxf(v1.x, v1.y), fmaxf(v1.z, v1.w));
    m0 = wave_max(m0); m1 = wave_max(m1);
    if (lane == 0) { red[0][wid] = m0; red[1][wid] = m1; }
    __syncthreads();
    m0 = fmaxf(fmaxf(red[0][0], red[0][1]), fmaxf(red[0][2], red[0][3]));
    m1 = fmaxf(fmaxf(red[1][0], red[1][1]), fmaxf(red[1][2], red[1][3]));

    float e0 = __expf(v0.x - m0) + __expf(v0.y - m0) + __expf(v0.z - m0) + __expf(v0.w - m0);
    float e1 = __expf(v1.x - m1) + __expf(v1.y - m1) + __expf(v1.z - m1) + __expf(v1.w - m1);
    e0 = wave_sum(e0); e1 = wave_sum(e1);
    if (lane == 0) { red[0][4 + wid] = e0; red[1][4 + wid] = e1; }
    __syncthreads();
    const float lse0 = m0 + __logf((red[0][4] + red[0][5]) + (red[0][6] + red[0][7]));
    const float lse1 = m1 + __logf((red[1][4] + red[1][5]) + (red[1][6] + red[1][7]));

    // state t: ext[t] = odd && t<S ? targets[t>>1] : blank(V-1); only RW states stored
    if (t < RW) {
        int ei = ((t & 1) && t < Sn) ? targets[b * Ln + (t >> 1)] : (Vn - 1);
        lp_ext[(size_t)r0 * RW + t]       = __expf(rows[0][ei] - lse0);
        lp_ext[(size_t)(r0 + 1) * RW + t] = __expf(rows[1][ei] - lse1);
    }
}

// Kernel 2: CTC forward recursion in SCALED LINEAR space.
// Staging: direct global->register float4 double-buffer (bufA/bufB, named arrays,
// fully unrolled -> stays in VGPRs). One global_load_dwordx4 stages a whole row
// (lane l's 16 B ARE its 4 states) — no LDS round-trip, no DMA fencing asm; the
// compiler scoreboard inserts exact vmcnt(N) waits per element, so tile tb+2's
// loads stay in flight across consume(tile tb+1) (one full consume ~ HBM RTT).
// 32 blocks x 1 wave: __launch_bounds__(64,1) frees the full 512-VGPR budget
// (2x128 VGPR tile buffers + state).
__global__ __launch_bounds__(64, 1) void ctc_kernel(const int* __restrict__ targets,
                                                    const float* __restrict__ lp_ext,
                                                    float* __restrict__ loss) {
    const int b    = blockIdx.x;
    const int lane = threadIdx.x;

    // skip flags (odd states only; even-register states never skip) as {0,1} floats
    float sk1f = 0.f, sk3f = 0.f;
    {
        const int* tg = targets + b * Ln;
        int s1 = 4 * lane + 1, s3 = 4 * lane + 3;
        if (s1 >= 3 && s1 < Sn) sk1f = (tg[s1 >> 1] != tg[(s1 - 3) >> 1]) ? 1.f : 0.f;
        if (s3 >= 3 && s3 < Sn) sk3f = (tg[s3 >> 1] != tg[(s3 - 3) >> 1]) ? 1.f : 0.f;
    }

    // lane l owns states 4l..4l+3 = row bytes [16l,16l+16). Rows are exactly 52
    // float4, so lanes >=52 clamp to lane 51's fragment (same cache line; their
    // m-state is contained garbage that only shifts upward, never back to s<=200).
    const float4* gb = (const float4*)(lp_ext + (size_t)b * Tn * RW);
    const int ll = (lane < 52) ? lane : 51;

    float4 bufA[TILE], bufB[TILE];
    #pragma unroll
    for (int u = 0; u < TILE; u++) bufA[u] = gb[(size_t)u * 52 + ll];
    #pragma unroll
    for (int u = 0; u < TILE; u++) bufB[u] = gb[(size_t)(TILE + u) * 52 + ll];

    // virtual alpha_{-1}: mass 1 at state 0 of lane 0; 1024 uniform steps follow.
    float m0 = (lane == 0) ? 1.0f : 0.0f, m1 = 0.f, m2 = 0.f, m3 = 0.f;
    int   E  = 0;     // per-lane scale: alpha = m * 2^E
    int   dE = 0;     // neighbor_E - E (constant between rescales)

    auto consume = [&](float4 (&pr)[TILE]) {
        #pragma unroll
        for (int u = 0; u < TILE; u++) {
            const float4 p = pr[u];
            float pmm = dpp_up1_f(m3);                          // lane0 -> 0
            float pm1 = __builtin_amdgcn_ldexpf(pmm, dE);       // align to local scale
            float n0 = (m0 + pm1) * p.x;                        // even s: no skip
            float n1 = fmaf(pm1, sk1f, m0 + m1) * p.y;
            float n2 = (m2 + m1) * p.z;                         // even s: no skip
            float n3 = fmaf(m1, sk3f, m2 + m3) * p.w;
            m0 = n0; m1 = n1; m2 = n2; m3 = n3;
            if ((u & 3) == 3) {   // rescale every 4 steps (p_min^4 ~ 2^-70: no flush)
                float mx = fmaxf(fmaxf(m0, m1), fmaxf(m2, m3));
                int k = __builtin_amdgcn_frexp_expf(mx);        // mx==0 -> 0
                int Enb_old = dpp_up1_i(E);                     // neighbor pre-rescale E
                E = (mx > 0.f) ? (E + k) : Enb_old;             // dead lanes: copy, NO offset
                m0 = __builtin_amdgcn_ldexpf(m0, -k);
                m1 = __builtin_amdgcn_ldexpf(m1, -k);
                m2 = __builtin_amdgcn_ldexpf(m2, -k);
                m3 = __builtin_amdgcn_ldexpf(m3, -k);
                dE = dpp_up1_i(E) - E;
            }
        }
    };

    const int nt = Tn / TILE;   // 32 tiles (even)
    for (int tb = 0; tb < nt; tb += 2) {
        consume(bufA);                          // tile tb
        if (tb + 2 < nt) {
            #pragma unroll
            for (int u = 0; u < TILE; u++)
                bufA[u] = gb[(size_t)((tb + 2) * TILE + u) * 52 + ll];
        }
        consume(bufB);                          // tile tb+1
        if (tb + 3 < nt) {
            #pragma unroll
            for (int u = 0; u < TILE; u++)
                bufB[u] = gb[(size_t)((tb + 3) * TILE + u) * 52 + ll];
        }
    }

    // alpha[200] = m0(lane50)*2^E50 ; alpha[199] = m3(lane49)*2^E49
    float q200 = __shfl(m0, 50); int E50 = __shfl(E, 50);
    float q199 = __shfl(m3, 49); int E49 = __shfl(E, 49);
    if (lane == 0) {
        float s = q200 + __builtin_amdgcn_ldexpf(q199, E49 - E50);
        loss[b] = -LN2F * ((float)E50 + __log2f(s));
    }
}

// Kernel 3: mean over B losses -> scalar (deterministic tree, kept for bit-exactness).
__global__ __launch_bounds__(64) void mean_kernel(const float* __restrict__ loss,
                                                  float* __restrict__ out) {
    int lane = threadIdx.x;
    float v = (lane < Bn) ? loss[lane] : 0.f;
    #pragma unroll
    for (int off = 32; off; off >>= 1) v += __shfl_xor(v, off);
    if (lane == 0) out[0] = v * (1.0f / Bn);
}

extern "C" void kernel_launch(void* const* d_in, const int* in_sizes, int n_in,
                              void* d_out, int out_size, void* d_ws, size_t ws_size,
                              hipStream_t stream) {
    const int*   targets = (const int*)d_in[0];
    const float* logits  = (const float*)d_in[1];

    // ws: lp_ext [B*T*RW floats = 27.26 MB] + loss[32]
    float* lp_ext = (float*)d_ws;
    float* loss   = (float*)((char*)d_ws + (size_t)Bn * Tn * RW * sizeof(float) + 4096);

    pre_kernel<<<Bn * Tn / 2, 256, 0, stream>>>(targets, logits, lp_ext);
    ctc_kernel<<<Bn, 64, 0, stream>>>(targets, lp_ext, loss);
    mean_kernel<<<1, 64, 0, stream>>>(loss, (float*)d_out);
}

// Round 2
// 237.890 us; speedup vs baseline: 1.0550x; 1.0550x over previous
//
#include <hip/hip_runtime.h>
#include <math.h>

#define DEV static __device__ __forceinline__

constexpr int Bn = 32, Tn = 1024, Vn = 1024, Ln = 100, Sn = 2 * Ln + 1; // S=201
constexpr int   PK   = 104;          // packed lp row: labels[0..99], blank, 0,0,0 (416 B, 16B-aligned)
constexpr float LN2F = 0.6931471805599453f;
constexpr int   TILE = 32;           // timesteps per register tile

// DPP wavefront shift-right by 1 (lane i <- lane i-1), VALU pipe — no LDS latency.
// dpp_ctrl 0x138 = WAVE_SHR1 (gfx9/CDNA). bound_ctrl=false -> lane 0 keeps `old`.
DEV float dpp_up1_f(float v) {                     // lane0 -> 0.0f
    return __builtin_bit_cast(float,
        __builtin_amdgcn_update_dpp(0, __builtin_bit_cast(int, v), 0x138, 0xf, 0xf, false));
}
DEV int dpp_up1_i(int v) {                         // lane0 -> own value (old = v)
    return __builtin_amdgcn_update_dpp(v, v, 0x138, 0xf, 0xf, false);
}

DEV float wave_max(float m) {
    #pragma unroll
    for (int off = 32; off; off >>= 1) m = fmaxf(m, __shfl_xor(m, off));
    return m;
}
DEV float wave_sum(float s) {
    #pragma unroll
    for (int off = 32; off; off >>= 1) s += __shfl_xor(s, off);
    return s;
}

// Kernel 1: two (b,t) rows per 256-thread block (2 independent loads -> MLP=2).
// Emits PROBABILITIES, PACKED rows of PK floats:
//   lp[row*PK + j] = exp(logits[row, targets[b,j]] - lse)   j<100
//   lp[row*PK +100]= exp(logits[row, blank] - lse) ; 101..103 = 0
// Same __expf inputs as the unpacked layout -> consumed values bit-identical.
__global__ __launch_bounds__(256) void pre_kernel(const int* __restrict__ targets,
                                                  const float* __restrict__ logits,
                                                  float* __restrict__ lp_ext,
                                                  int* __restrict__ cnt) {
    __shared__ float rows[2][Vn];     // 8 KB
    __shared__ float red[2][8];
    const int t    = threadIdx.x;
    const int lane = t & 63;
    const int wid  = t >> 6;
    const int r0   = blockIdx.x * 2;      // rows r0, r0+1 share the same b (Tn even)
    const int b    = r0 >> 10;

    if (blockIdx.x == 0 && t == 0) cnt[0] = 0;   // reset ticket for this iteration

    float4 v0 = ((const float4*)(logits + (size_t)r0 * Vn))[t];
    float4 v1 = ((const float4*)(logits + (size_t)(r0 + 1) * Vn))[t];
    ((float4*)rows[0])[t] = v0;
    ((float4*)rows[1])[t] = v1;

    float m0 = fmaxf(fmaxf(v0.x, v0.y), fmaxf(v0.z, v0.w));
    float m1 = fmaxf(fmaxf(v1.x, v1.y), fmaxf(v1.z, v1.w));
    m0 = wave_max(m0); m1 = wave_max(m1);
    if (lane == 0) { red[0][wid] = m0; red[1][wid] = m1; }
    __syncthreads();
    m0 = fmaxf(fmaxf(red[0][0], red[0][1]), fmaxf(red[0][2], red[0][3]));
    m1 = fmaxf(fmaxf(red[1][0], red[1][1]), fmaxf(red[1][2], red[1][3]));

    float e0 = __expf(v0.x - m0) + __expf(v0.y - m0) + __expf(v0.z - m0) + __expf(v0.w - m0);
    float e1 = __expf(v1.x - m1) + __expf(v1.y - m1) + __expf(v1.z - m1) + __expf(v1.w - m1);
    e0 = wave_sum(e0); e1 = wave_sum(e1);
    if (lane == 0) { red[0][4 + wid] = e0; red[1][4 + wid] = e1; }
    __syncthreads();
    const float lse0 = m0 + __logf((red[0][4] + red[0][5]) + (red[0][6] + red[0][7]));
    const float lse1 = m1 + __logf((red[1][4] + red[1][5]) + (red[1][6] + red[1][7]));

    if (t < PK) {
        float w0, w1;
        if (t < 100) {
            int ei = targets[b * Ln + t];
            w0 = __expf(rows[0][ei] - lse0);
            w1 = __expf(rows[1][ei] - lse1);
        } else if (t == 100) {
            w0 = __expf(rows[0][Vn - 1] - lse0);
            w1 = __expf(rows[1][Vn - 1] - lse1);
        } else {
            w0 = 0.f; w1 = 0.f;
        }
        lp_ext[(size_t)r0 * PK + t]       = w0;
        lp_ext[(size_t)(r0 + 1) * PK + t] = w1;
    }
}

// Kernel 2: CTC forward recursion in SCALED LINEAR space, packed-row loads.
// Lane l owns states 4l..4l+3: p = (blank, lab[2l], blank, lab[2l+1]).
// Lanes >=52 clamp to l=51 (reads (0,0) pad, stays in-row); their state only
// shifts upward, never back into s<=200; rescales are exact powers of 2, so the
// final scalar is bit-identical to the unpacked version.
// Direct global->register float2+scalar double-buffer; compiler scoreboard
// handles vmcnt. __launch_bounds__(64,1): full 512-VGPR budget for the buffers.
// The LAST block to finish (atomic ticket) also does the mean — removes the
// third dispatch; the reduction tree is the exact same shuffle tree as before.
__global__ __launch_bounds__(64, 1) void ctc_kernel(const int* __restrict__ targets,
                                                    const float* __restrict__ lp_ext,
                                                    float* __restrict__ loss,
                                                    int* __restrict__ cnt,
                                                    float* __restrict__ out) {
    const int b    = blockIdx.x;
    const int lane = threadIdx.x;

    // skip flags (odd states only; even-register states never skip) as {0,1} floats
    float sk1f = 0.f, sk3f = 0.f;
    {
        const int* tg = targets + b * Ln;
        int s1 = 4 * lane + 1, s3 = 4 * lane + 3;
        if (s1 >= 3 && s1 < Sn) sk1f = (tg[s1 >> 1] != tg[(s1 - 3) >> 1]) ? 1.f : 0.f;
        if (s3 >= 3 && s3 < Sn) sk3f = (tg[s3 >> 1] != tg[(s3 - 3) >> 1]) ? 1.f : 0.f;
    }

    const float* gb = lp_ext + (size_t)b * Tn * PK;
    const int ll = (lane < 51) ? lane : 51;   // lane50 -> (blank,0); lane51 -> (0,0)

    float2 lA[TILE], lB[TILE];
    float  bA[TILE], bB[TILE];
    #pragma unroll
    for (int u = 0; u < TILE; u++) {
        const float* row = gb + (size_t)u * PK;
        lA[u] = ((const float2*)row)[ll];
        bA[u] = row[100];
    }
    #pragma unroll
    for (int u = 0; u < TILE; u++) {
        const float* row = gb + (size_t)(TILE + u) * PK;
        lB[u] = ((const float2*)row)[ll];
        bB[u] = row[100];
    }

    // virtual alpha_{-1}: mass 1 at state 0 of lane 0; 1024 uniform steps follow.
    float m0 = (lane == 0) ? 1.0f : 0.0f, m1 = 0.f, m2 = 0.f, m3 = 0.f;
    int   E  = 0;     // per-lane scale: alpha = m * 2^E
    int   dE = 0;     // neighbor_E - E (constant between rescales)

    auto consume = [&](float2 (&lb)[TILE], float (&bb)[TILE]) {
        #pragma unroll
        for (int u = 0; u < TILE; u++) {
            const float2 lp = lb[u];
            const float  bl = bb[u];
            float pmm = dpp_up1_f(m3);                          // lane0 -> 0
            float pm1 = __builtin_amdgcn_ldexpf(pmm, dE);       // align to local scale
            float n0 = (m0 + pm1) * bl;                         // even s: blank, no skip
            float n1 = fmaf(pm1, sk1f, m0 + m1) * lp.x;
            float n2 = (m2 + m1) * bl;                          // even s: blank, no skip
            float n3 = fmaf(m1, sk3f, m2 + m3) * lp.y;
            m0 = n0; m1 = n1; m2 = n2; m3 = n3;
            if ((u & 3) == 3) {   // rescale every 4 steps (exact powers of 2)
                float mx = fmaxf(fmaxf(m0, m1), fmaxf(m2, m3));
                int k = __builtin_amdgcn_frexp_expf(mx);        // mx==0 -> 0
                int Enb_old = dpp_up1_i(E);                     // neighbor pre-rescale E
                E = (mx > 0.f) ? (E + k) : Enb_old;             // dead lanes: copy, NO offset
                m0 = __builtin_amdgcn_ldexpf(m0, -k);
                m1 = __builtin_amdgcn_ldexpf(m1, -k);
                m2 = __builtin_amdgcn_ldexpf(m2, -k);
                m3 = __builtin_amdgcn_ldexpf(m3, -k);
                dE = dpp_up1_i(E) - E;
            }
        }
    };

    const int nt = Tn / TILE;   // 32 tiles (even)
    for (int tb = 0; tb < nt; tb += 2) {
        consume(lA, bA);                        // tile tb
        if (tb + 2 < nt) {
            #pragma unroll
            for (int u = 0; u < TILE; u++) {
                const float* row = gb + (size_t)((tb + 2) * TILE + u) * PK;
                lA[u] = ((const float2*)row)[ll];
                bA[u] = row[100];
            }
        }
        consume(lB, bB);                        // tile tb+1
        if (tb + 3 < nt) {
            #pragma unroll
            for (int u = 0; u < TILE; u++) {
                const float* row = gb + (size_t)((tb + 3) * TILE + u) * PK;
                lB[u] = ((const float2*)row)[ll];
                bB[u] = row[100];
            }
        }
    }

    // alpha[200] = m0(lane50)*2^E50 ; alpha[199] = m3(lane49)*2^E49
    float q200 = __shfl(m0, 50); int E50 = __shfl(E, 50);
    float q199 = __shfl(m3, 49); int E49 = __shfl(E, 49);
    if (lane == 0) {
        float s = q200 + __builtin_amdgcn_ldexpf(q199, E49 - E50);
        loss[b] = -LN2F * ((float)E50 + __log2f(s));
    }

    // last-block-out mean (exact same shuffle tree as the old mean_kernel)
    __threadfence();
    int ticket = 0;
    if (lane == 0) ticket = atomicAdd(cnt, 1);
    ticket = __shfl(ticket, 0);
    if (ticket == Bn - 1) {
        __threadfence();
        float v = (lane < Bn) ? ((volatile const float*)loss)[lane] : 0.f;
        #pragma unroll
        for (int off = 32; off; off >>= 1) v += __shfl_xor(v, off);
        if (lane == 0) out[0] = v * (1.0f / Bn);
    }
}

extern "C" void kernel_launch(void* const* d_in, const int* in_sizes, int n_in,
                              void* d_out, int out_size, void* d_ws, size_t ws_size,
                              hipStream_t stream) {
    const int*   targets = (const int*)d_in[0];
    const float* logits  = (const float*)d_in[1];

    // ws: lp_ext [B*T*PK floats = 13.63 MB] + loss[32] + cnt
    float* lp_ext = (float*)d_ws;
    char*  tail   = (char*)d_ws + (size_t)Bn * Tn * PK * sizeof(float) + 4096;
    float* loss   = (float*)tail;
    int*   cnt    = (int*)(tail + 256);

    pre_kernel<<<Bn * Tn / 2, 256, 0, stream>>>(targets, logits, lp_ext, cnt);
    ctc_kernel<<<Bn, 64, 0, stream>>>(targets, lp_ext, loss, cnt, (float*)d_out);
}